// Round 2
// baseline (479.752 us; speedup 1.0000x reference)
//
#include <hip/hip_runtime.h>
#include <float.h>
#include <math.h>

// NNConv net: 2x edge-conditioned conv (scalar edge attr) + 2 FC + log_softmax.
// W_e = a_e*U_s + V_s over <=26 breakpoint segments of the scalar edge attr.
// Edges bucketed by segment (chunk-aligned so a wave chunk is single-segment);
// per wave: U/V columns register-cached (lane = out channel), per-lane metadata
// gather + readlane broadcast, unrolled break-free chunk loop.
// R3: killed scratch demotion of Ur/Vr + fused node2+fc1+fc2.
// R4: tail_kernel rebatched to 4 nodes/wave; REGRESSED: allocator targeted
// 8 waves/EU (VGPR_Count=64) and spilled the whole register cache -> 677 MB
// scratch traffic, 310 us.
// R5: __launch_bounds__(256, 4) on tail -> 128-VGPR budget, spill eliminated.

#define NCONST 25
#define CH1 32   // edges per wave chunk, conv1
#define CH2 16   // edges per wave chunk, conv2
#define PACK_MASK 0x1FFFF  // edge id < 2^17 (E = 100000)
#define TNB 4    // nodes per wave in tail

__device__ __forceinline__ void atomicMaxFloat(float* addr, float val) {
    if (val >= 0.f) atomicMax((int*)addr, __float_as_int(val));
    else            atomicMin((unsigned int*)addr, __float_as_uint(val));
}
__device__ __forceinline__ float readlane_f(float v, int l) {
    return __int_as_float(__builtin_amdgcn_readlane(__float_as_int(v), l));
}

// Fill: agg regions with -FLT_MAX, order arrays with -1, hist with 0.
__global__ void fill_kernel(float* agg, int nAgg, int* ords, int nOrd, int* hist, int nH) {
    int i = blockIdx.x * blockDim.x + threadIdx.x;
    int stride = gridDim.x * blockDim.x;
    int total = nAgg + nOrd + nH;
    for (; i < total; i += stride) {
        if (i < nAgg) agg[i] = -FLT_MAX;
        else if (i < nAgg + nOrd) ords[i - nAgg] = -1;
        else hist[i - nAgg - nOrd] = 0;
    }
}

// Per edge: segment rank for both convs (j = #breakpoints < a), LDS-aggregated
// histograms, store packed (j1 | j2<<8).
__global__ void assign_hist_kernel(const float* __restrict__ ea,
                                   const float* __restrict__ w1a, const float* __restrict__ b1a,
                                   const float* __restrict__ w2a, const float* __restrict__ b2a,
                                   int E, int* __restrict__ segpack, int* __restrict__ hist) {
    __shared__ float t1[NCONST], t2[NCONST];
    __shared__ int lh[64];
    int tid = threadIdx.x;
    if (tid < NCONST) {
        float w = w1a[tid]; t1[tid] = (w != 0.f) ? (-b1a[tid] / w) : INFINITY;
        float v = w2a[tid]; t2[tid] = (v != 0.f) ? (-b2a[tid] / v) : INFINITY;
    }
    if (tid < 64) lh[tid] = 0;
    __syncthreads();
    int e = blockIdx.x * blockDim.x + tid;
    bool valid = e < E;
    if (valid) {
        float a = ea[e];
        int j1 = 0, j2 = 0;
        for (int k = 0; k < NCONST; ++k) { j1 += (t1[k] < a); j2 += (t2[k] < a); }
        segpack[e] = j1 | (j2 << 8);
        atomicAdd(&lh[j1], 1); atomicAdd(&lh[32 + j2], 1);
    }
    __syncthreads();
    if (tid < 64 && lh[tid]) atomicAdd(&hist[tid], lh[tid]);
}

// Parallel hist load through LDS, then two lanes do the 26-step chunk-aligned
// exclusive scan LDS-resident.
__global__ void scanpad_kernel(const int* __restrict__ hist, int* __restrict__ cur) {
    __shared__ int h[64];
    int tid = threadIdx.x;
    h[tid] = hist[tid];
    __syncthreads();
    if (tid == 0) {
        int off = 0;
        for (int j = 0; j < 26; ++j) { cur[j] = off; off += ((h[j] + CH1 - 1) / CH1) * CH1; }
    } else if (tid == 1) {
        int off = 0;
        for (int j = 0; j < 26; ++j) { cur[32 + j] = off; off += ((h[32 + j] + CH2 - 1) / CH2) * CH2; }
    }
}

// Block-aggregated scatter: LDS rank + one global atomicAdd per (block,bin).
__global__ void scatter_kernel(const int* __restrict__ segpack, int E, int* __restrict__ cur,
                               int* __restrict__ order1, int* __restrict__ order2) {
    __shared__ int lh[64], lb[64];
    int tid = threadIdx.x;
    if (tid < 64) lh[tid] = 0;
    __syncthreads();
    int e = blockIdx.x * blockDim.x + tid;
    bool valid = e < E;
    int j1 = 0, j2 = 0, r1 = 0, r2 = 0;
    if (valid) {
        int p = segpack[e]; j1 = p & 0xFF; j2 = p >> 8;
        r1 = atomicAdd(&lh[j1], 1); r2 = atomicAdd(&lh[32 + j2], 1);
    }
    __syncthreads();
    if (tid < 64 && lh[tid]) lb[tid] = atomicAdd(&cur[tid], lh[tid]);
    __syncthreads();
    if (valid) {
        order1[lb[j1] + r1] = (j1 << 17) | e;
        order2[lb[32 + j2] + r2] = (j2 << 17) | e;
    }
}

// U_s = sum_{k active} wa_k*wb_k ; V_s = sum_{k active} ba_k*wb_k + bb.
__global__ void build_uv_fused(const float* w1a, const float* b1a, const float* w1b, const float* b1b,
                               const float* w2a, const float* b2a, const float* w2b, const float* b2b,
                               float* U1, float* V1, float* U2, float* V2) {
    __shared__ float swa[NCONST], sba[NCONST], st[NCONST];
    __shared__ int sr[NCONST];
    __shared__ unsigned msk_sh;
    int seg = blockIdx.y;
    int bx = blockIdx.x;
    int conv = (bx < 2) ? 0 : 1;
    const float* wa = conv ? w2a : w1a;
    const float* ba = conv ? b2a : b1a;
    int tid = threadIdx.x;
    if (tid < NCONST) {
        float w = wa[tid], b = ba[tid];
        swa[tid] = w; sba[tid] = b;
        st[tid] = (w != 0.f) ? (-b / w) : INFINITY;
    }
    __syncthreads();
    if (tid < NCONST) {
        int rk = 0;
        for (int l = 0; l < NCONST; ++l) rk += (st[l] < st[tid]) ? 1 : 0;
        sr[tid] = rk;
    }
    __syncthreads();
    if (tid == 0) {
        unsigned m = 0;
        for (int k = 0; k < NCONST; ++k) {
            float w = swa[k];
            bool act = (w > 0.f) ? (seg > sr[k])
                     : (w < 0.f) ? (seg <= sr[k])
                                 : (sba[k] > 0.f);
            if (act) m |= (1u << k);
        }
        msk_sh = m;
    }
    __syncthreads();
    unsigned msk = msk_sh;
    if (conv == 0) {
        int idx = bx * 256 + tid;           // < 512
        float u = 0.f, v = 0.f;
        for (int k = 0; k < NCONST; ++k)
            if (msk & (1u << k)) { float w = w1b[k * 512 + idx]; u = fmaf(swa[k], w, u); v = fmaf(sba[k], w, v); }
        v += b1b[idx];
        U1[seg * 512 + idx] = u; V1[seg * 512 + idx] = v;
    } else {
        int idx = (bx - 2) * 256 + tid;     // < 2048
        float u = 0.f, v = 0.f;
        for (int k = 0; k < NCONST; ++k)
            if (msk & (1u << k)) { float w = w2b[k * 2048 + idx]; u = fmaf(swa[k], w, u); v = fmaf(sba[k], w, v); }
        v += b2b[idx];
        U2[seg * 2048 + idx] = u; V2[seg * 2048 + idx] = v;
    }
}

// conv1 edges: IC=16, OC=32, half-wave per edge (2 edges/iter).
__global__ void edge1_kernel(const float* __restrict__ xin, const int* __restrict__ src,
                             const int* __restrict__ tgt, const float* __restrict__ ea,
                             const int* __restrict__ order, int cap,
                             const float* __restrict__ U, const float* __restrict__ V,
                             float* __restrict__ agg) {
    int wid = (blockIdx.x * blockDim.x + threadIdx.x) >> 6;
    int lane = threadIdx.x & 63;
    int base = wid * CH1;
    if (base >= cap) return;
    int pk = order[base + (lane & (CH1 - 1))];
    int p0 = __builtin_amdgcn_readfirstlane(pk);
    if (p0 < 0) return;                        // whole-pad chunk past used region
    int seg = p0 >> 17;
    int ev = (pk < 0) ? 0 : (pk & PACK_MASK);
    int sv = src[ev], tv = tgt[ev];
    float av = ea[ev];
    int half = lane >> 5, c = lane & 31;
    float Ur[16], Vr[16];
    {
        const float* Us = U + seg * 512 + c;
        const float* Vs = V + seg * 512 + c;
#pragma unroll
        for (int i = 0; i < 16; ++i) { Ur[i] = Us[i * 32]; Vr[i] = Vs[i * 32]; }
    }
#pragma unroll
    for (int t = 0; t < CH1; t += 2) {
        int pA = __builtin_amdgcn_readlane(pk, t);
        int pB = __builtin_amdgcn_readlane(pk, t + 1);
        int sA = __builtin_amdgcn_readlane(sv, t);
        int sB = __builtin_amdgcn_readlane(sv, t + 1);
        int tA = __builtin_amdgcn_readlane(tv, t);
        int tB = __builtin_amdgcn_readlane(tv, t + 1);
        float aA = readlane_f(av, t);
        float aB = readlane_f(av, t + 1);
        const float* xA = xin + sA * 16;
        const float* xB = xin + sB * 16;
        float ah = half ? aB : aA;
        int   th = half ? tB : tA;
        int   ph = half ? pB : pA;
        float acc = 0.f;
#pragma unroll
        for (int i = 0; i < 16; ++i) {
            float xi = half ? xB[i] : xA[i];
            acc = fmaf(xi, fmaf(ah, Ur[i], Vr[i]), acc);
        }
        if (ph >= 0) atomicMaxFloat(&agg[th * 32 + c], acc);
    }
}

// conv2 edges: IC=32, OC=64, lane = out channel, A/B edge pair per iteration.
__global__ void edge2_kernel(const float* __restrict__ xin, const int* __restrict__ src,
                             const int* __restrict__ tgt, const float* __restrict__ ea,
                             const int* __restrict__ order, int cap,
                             const float* __restrict__ U, const float* __restrict__ V,
                             float* __restrict__ agg) {
    int wid = (blockIdx.x * blockDim.x + threadIdx.x) >> 6;
    int lane = threadIdx.x & 63;
    int base = wid * CH2;
    if (base >= cap) return;
    int pk = order[base + (lane & (CH2 - 1))];
    int p0 = __builtin_amdgcn_readfirstlane(pk);
    if (p0 < 0) return;
    int seg = p0 >> 17;
    int ev = (pk < 0) ? 0 : (pk & PACK_MASK);
    int sv = src[ev], tv = tgt[ev];
    float av = ea[ev];
    float Ur[32], Vr[32];
    {
        const float* Us = U + seg * 2048 + lane;
        const float* Vs = V + seg * 2048 + lane;
#pragma unroll
        for (int i = 0; i < 32; ++i) { Ur[i] = Us[i * 64]; Vr[i] = Vs[i * 64]; }
    }
#pragma unroll
    for (int t = 0; t < CH2; t += 2) {
        int pA = __builtin_amdgcn_readlane(pk, t);
        int pB = __builtin_amdgcn_readlane(pk, t + 1);
        int sA = __builtin_amdgcn_readlane(sv, t);
        int sB = __builtin_amdgcn_readlane(sv, t + 1);
        int tA = __builtin_amdgcn_readlane(tv, t);
        int tB = __builtin_amdgcn_readlane(tv, t + 1);
        float aA = readlane_f(av, t);
        float aB = readlane_f(av, t + 1);
        const float* xA = xin + sA * 32;
        const float* xB = xin + sB * 32;
        float accA = 0.f, accB = 0.f;
#pragma unroll
        for (int i = 0; i < 32; ++i) {
            accA = fmaf(xA[i], fmaf(aA, Ur[i], Vr[i]), accA);
            accB = fmaf(xB[i], fmaf(aB, Ur[i], Vr[i]), accB);
        }
        if (pA >= 0) atomicMaxFloat(&agg[tA * 64 + lane], accA);
        if (pB >= 0) atomicMaxFloat(&agg[tB * 64 + lane], accB);
    }
}

// conv1 node update: out = elu( fixup(agg) + x @ wr1 + bias1 )
__global__ void node1_kernel(const float* __restrict__ xin, const float* __restrict__ agg,
                             const float* __restrict__ wroot, const float* __restrict__ bias,
                             float* __restrict__ out, int N) {
    int idx = blockIdx.x * blockDim.x + threadIdx.x;
    if (idx >= N * 32) return;
    int n = idx >> 5, c = idx & 31;
    float v = agg[idx];
    if (v == -FLT_MAX) v = 0.f;
    float acc = v + bias[c];
#pragma unroll
    for (int i = 0; i < 16; ++i) acc = fmaf(xin[n * 16 + i], wroot[i * 32 + c], acc);
    out[idx] = acc > 0.f ? acc : expm1f(acc);
}

// Fused tail: node2 (agg fixup + root matmul + elu) -> fc1+elu -> fc2+log_softmax.
// R4: TNB=4 nodes per wave, 16 nodes/block. All hot-path data exchange is
// wave-local LDS (no __syncthreads in the per-node flow). wr2 column cached in
// 32 VGPRs reused across the 4 nodes; fc1 weight loads amortized 4x; fc2 runs
// all 64 lanes as (n = lane>>4, j = lane&15) against an LDS-transposed fc2w;
// softmax = 16-wide shfl_xor reduce.
// R5: __launch_bounds__(256, 4) -> 128-VGPR budget (default 8-waves/EU target
// capped at 64 VGPRs and spilled wreg/accs -> 677 MB scratch traffic).
__global__ void __launch_bounds__(256, 4)
tail_kernel(const float* __restrict__ h1, const float* __restrict__ agg2,
            const float* __restrict__ wr2, const float* __restrict__ bias2,
            const float* __restrict__ fc1w, const float* __restrict__ fc1b,
            const float* __restrict__ fc2w, const float* __restrict__ fc2b,
            float* __restrict__ out) {
    __shared__ __align__(16) float h1sh[4][TNB][32];
    __shared__ __align__(16) float h2sh[4][TNB][64];
    __shared__ __align__(16) float h3sh[4][TNB][132];   // +4 pad: n-rows spread banks
    __shared__ __align__(16) float wTsh[10][132];       // fc2w transposed [class][k]
    int tid = threadIdx.x;
    int wv = tid >> 6, lane = tid & 63;

    // one-time staging: wTsh[j][k] = fc2w[k*10+j] (block-cooperative)
    for (int t = tid; t < 1280; t += 256) {
        int k = t / 10, j = t - k * 10;
        wTsh[j][k] = fc2w[t];
    }
    __syncthreads();   // only barrier; everything below is wave-local

    int nb = blockIdx.x * (4 * TNB) + wv * TNB;   // base node of this wave

    // cooperative h1 row stage: TNB*32 = 128 floats = one float2 per lane
    {
        const float2* hp = (const float2*)(h1 + (size_t)nb * 32);
        ((float2*)&h1sh[wv][0][0])[lane] = hp[lane];
    }

    // ---- phase 1: node2. lane = out channel c (0..63), loop over 4 nodes ----
    float wreg[32];
#pragma unroll
    for (int i = 0; i < 32; ++i) wreg[i] = wr2[i * 64 + lane];
    float b2 = bias2[lane];
#pragma unroll
    for (int n = 0; n < TNB; ++n) {
        float v = agg2[(size_t)(nb + n) * 64 + lane];
        if (v == -FLT_MAX) v = 0.f;
        float acc = v + b2;
        const float4* hv = (const float4*)h1sh[wv][n];   // broadcast reads
#pragma unroll
        for (int q = 0; q < 8; ++q) {
            float4 h = hv[q];
            acc = fmaf(h.x, wreg[q * 4 + 0], acc);
            acc = fmaf(h.y, wreg[q * 4 + 1], acc);
            acc = fmaf(h.z, wreg[q * 4 + 2], acc);
            acc = fmaf(h.w, wreg[q * 4 + 3], acc);
        }
        h2sh[wv][n][lane] = acc > 0.f ? acc : expm1f(acc);
    }

    // ---- phase 2: fc1. outputs o1 = lane, o2 = lane+64, 4 nodes each ----
    float acc1[TNB], acc2[TNB];
    {
        float fb1 = fc1b[lane], fb2 = fc1b[64 + lane];
#pragma unroll
        for (int n = 0; n < TNB; ++n) { acc1[n] = fb1; acc2[n] = fb2; }
    }
#pragma unroll
    for (int q = 0; q < 16; ++q) {
        float wa0 = fc1w[(q * 4 + 0) * 128 + lane];
        float wb0 = fc1w[(q * 4 + 0) * 128 + 64 + lane];
        float wa1 = fc1w[(q * 4 + 1) * 128 + lane];
        float wb1 = fc1w[(q * 4 + 1) * 128 + 64 + lane];
        float wa2 = fc1w[(q * 4 + 2) * 128 + lane];
        float wb2 = fc1w[(q * 4 + 2) * 128 + 64 + lane];
        float wa3 = fc1w[(q * 4 + 3) * 128 + lane];
        float wb3 = fc1w[(q * 4 + 3) * 128 + 64 + lane];
#pragma unroll
        for (int n = 0; n < TNB; ++n) {
            float4 h = ((const float4*)h2sh[wv][n])[q];  // broadcast read
            acc1[n] = fmaf(h.x, wa0, acc1[n]); acc2[n] = fmaf(h.x, wb0, acc2[n]);
            acc1[n] = fmaf(h.y, wa1, acc1[n]); acc2[n] = fmaf(h.y, wb1, acc2[n]);
            acc1[n] = fmaf(h.z, wa2, acc1[n]); acc2[n] = fmaf(h.z, wb2, acc2[n]);
            acc1[n] = fmaf(h.w, wa3, acc1[n]); acc2[n] = fmaf(h.w, wb3, acc2[n]);
        }
    }
#pragma unroll
    for (int n = 0; n < TNB; ++n) {
        float a = acc1[n], b = acc2[n];
        h3sh[wv][n][lane]      = a > 0.f ? a : expm1f(a);
        h3sh[wv][n][64 + lane] = b > 0.f ? b : expm1f(b);
    }

    // ---- phase 3: fc2 + log_softmax. lane -> (n = lane>>4, j = lane&15) ----
    {
        int n = lane >> 4, j = lane & 15;
        bool act = j < 10;
        int jc = act ? j : 0;
        float a = fc2b[jc];
        const float4* h3v = (const float4*)h3sh[wv][n];
        const float4* wv4 = (const float4*)wTsh[jc];
#pragma unroll
        for (int q = 0; q < 32; ++q) {
            float4 h = h3v[q];
            float4 w = wv4[q];
            a = fmaf(h.x, w.x, a);
            a = fmaf(h.y, w.y, a);
            a = fmaf(h.z, w.z, a);
            a = fmaf(h.w, w.w, a);
        }
        float lm = act ? a : -FLT_MAX;
        lm = fmaxf(lm, __shfl_xor(lm, 1, 16));
        lm = fmaxf(lm, __shfl_xor(lm, 2, 16));
        lm = fmaxf(lm, __shfl_xor(lm, 4, 16));
        lm = fmaxf(lm, __shfl_xor(lm, 8, 16));
        float ls = act ? expf(a - lm) : 0.f;
        ls += __shfl_xor(ls, 1, 16);
        ls += __shfl_xor(ls, 2, 16);
        ls += __shfl_xor(ls, 4, 16);
        ls += __shfl_xor(ls, 8, 16);
        if (act) out[(size_t)(nb + n) * 10 + j] = a - lm - logf(ls);
    }
}

extern "C" void kernel_launch(void* const* d_in, const int* in_sizes, int n_in,
                              void* d_out, int out_size, void* d_ws, size_t ws_size,
                              hipStream_t stream) {
    const float* x     = (const float*)d_in[0];
    const int*   eidx  = (const int*)d_in[1];
    const float* ea    = (const float*)d_in[2];
    const float* w1a   = (const float*)d_in[3];
    const float* b1a   = (const float*)d_in[4];
    const float* w1b   = (const float*)d_in[5];
    const float* b1b   = (const float*)d_in[6];
    const float* wr1   = (const float*)d_in[7];
    const float* bias1 = (const float*)d_in[8];
    const float* w2a   = (const float*)d_in[9];
    const float* b2a   = (const float*)d_in[10];
    const float* w2b   = (const float*)d_in[11];
    const float* b2b   = (const float*)d_in[12];
    const float* wr2   = (const float*)d_in[13];
    const float* bias2 = (const float*)d_in[14];
    const float* fc1w  = (const float*)d_in[15];
    const float* fc1b  = (const float*)d_in[16];
    const float* fc2w  = (const float*)d_in[17];
    const float* fc2b  = (const float*)d_in[18];

    const int N = in_sizes[0] / 16;   // 20000
    const int E = in_sizes[2];        // 100000
    const int* src = eidx;
    const int* tgt = eidx + E;

    const int cap1 = ((E + 26 * (CH1 - 1)) + CH1 - 1) / CH1 * CH1;
    const int cap2 = ((E + 26 * (CH2 - 1)) + CH2 - 1) / CH2 * CH2;

    float* ws = (float*)d_ws;
    size_t off = 0;
    int*      hist = (int*)(ws + off);      off += 64;
    int*      cur  = (int*)(ws + off);      off += 64;
    int*      segp = (int*)(ws + off);      off += E;
    int*      ord1 = (int*)(ws + off);      off += cap1;   // ord1/ord2 contiguous
    int*      ord2 = (int*)(ws + off);      off += cap2;
    float*    U1   = ws + off;              off += 26 * 512;
    float*    V1   = ws + off;              off += 26 * 512;
    float*    U2   = ws + off;              off += 26 * 2048;
    float*    V2   = ws + off;              off += 26 * 2048;
    float*    AGG1 = ws + off;              off += (size_t)N * 32;   // AGG1/AGG2 contiguous
    float*    AGG2 = ws + off;              off += (size_t)N * 64;
    float*    H1b  = ws + off;              off += (size_t)N * 32;

    // 1. init: agg=-FLT_MAX, order arrays=-1, hist=0
    fill_kernel<<<512, 256, 0, stream>>>(AGG1, N * 96, ord1, cap1 + cap2, hist, 64);
    // 2. per-edge segment ranks + histograms
    assign_hist_kernel<<<(E + 255) / 256, 256, 0, stream>>>(ea, w1a, b1a, w2a, b2a, E, segp, hist);
    // 3. chunk-aligned bucket offsets
    scanpad_kernel<<<1, 64, 0, stream>>>(hist, cur);
    // 4. scatter edges into segment-sorted order arrays
    scatter_kernel<<<(E + 255) / 256, 256, 0, stream>>>(segp, E, cur, ord1, ord2);
    // 5. per-segment U/V tables, both convs
    build_uv_fused<<<dim3(10, 26), 256, 0, stream>>>(w1a, b1a, w1b, b1b, w2a, b2a, w2b, b2b,
                                                     U1, V1, U2, V2);
    // 6. conv1
    {
        int waves = cap1 / CH1;
        edge1_kernel<<<(waves + 3) / 4, 256, 0, stream>>>(x, src, tgt, ea, ord1, cap1, U1, V1, AGG1);
    }
    node1_kernel<<<(N * 32 + 255) / 256, 256, 0, stream>>>(x, AGG1, wr1, bias1, H1b, N);
    // 7. conv2
    {
        int waves = cap2 / CH2;
        edge2_kernel<<<(waves + 3) / 4, 256, 0, stream>>>(H1b, src, tgt, ea, ord2, cap2, U2, V2, AGG2);
    }
    // 8. fused node2 + fc1 + fc2 + log_softmax (N % 16 == 0 -> 16 nodes/block)
    tail_kernel<<<N / 16, 256, 0, stream>>>(H1b, AGG2, wr2, bias2, fc1w, fc1b, fc2w, fc2b, (float*)d_out);
}

// Round 4
// 198.208 us; speedup vs baseline: 2.4205x; 2.4205x over previous
//
#include <hip/hip_runtime.h>
#include <float.h>
#include <math.h>

// NNConv net: 2x edge-conditioned conv (scalar edge attr) + 2 FC + log_softmax.
// W_e = a_e*U_s + V_s over <=26 breakpoint segments of the scalar edge attr.
// Edges bucketed by segment (chunk-aligned so a wave chunk is single-segment);
// per wave: U/V columns register-cached (lane = out channel), per-lane metadata
// gather + readlane broadcast, unrolled break-free chunk loop.
// R3: killed scratch demotion of Ur/Vr + fused node2+fc1+fc2 (53.5 us tail).
// R4: tail rebatched to 4 nodes/wave with wreg[32]+acc arrays; REGRESSED:
// allocator pinned 64-VGPR budget and spilled -> 677 MB scratch, 310 us.
// R5: __launch_bounds__(256,4) was a NO-OP (VGPR_Count still 64, same spill).
// R6: zero-local-array rewrite; FAILED: fc1 k-loop bound 32 instead of 16
// (fc1 input dim is 64 -> 16 float4 groups) -> OOB weight + LDS reads.
// R7: fix k4 < 16. Structure of R6 otherwise unchanged.

#define NCONST 25
#define CH1 32   // edges per wave chunk, conv1
#define CH2 16   // edges per wave chunk, conv2
#define PACK_MASK 0x1FFFF  // edge id < 2^17 (E = 100000)
#define TNB 4    // nodes per wave in tail

__device__ __forceinline__ void atomicMaxFloat(float* addr, float val) {
    if (val >= 0.f) atomicMax((int*)addr, __float_as_int(val));
    else            atomicMin((unsigned int*)addr, __float_as_uint(val));
}
__device__ __forceinline__ float readlane_f(float v, int l) {
    return __int_as_float(__builtin_amdgcn_readlane(__float_as_int(v), l));
}
__device__ __forceinline__ float elu_f(float a) {
    return a > 0.f ? a : expm1f(a);
}

// Fill: agg regions with -FLT_MAX, order arrays with -1, hist with 0.
__global__ void fill_kernel(float* agg, int nAgg, int* ords, int nOrd, int* hist, int nH) {
    int i = blockIdx.x * blockDim.x + threadIdx.x;
    int stride = gridDim.x * blockDim.x;
    int total = nAgg + nOrd + nH;
    for (; i < total; i += stride) {
        if (i < nAgg) agg[i] = -FLT_MAX;
        else if (i < nAgg + nOrd) ords[i - nAgg] = -1;
        else hist[i - nAgg - nOrd] = 0;
    }
}

// Per edge: segment rank for both convs (j = #breakpoints < a), LDS-aggregated
// histograms, store packed (j1 | j2<<8).
__global__ void assign_hist_kernel(const float* __restrict__ ea,
                                   const float* __restrict__ w1a, const float* __restrict__ b1a,
                                   const float* __restrict__ w2a, const float* __restrict__ b2a,
                                   int E, int* __restrict__ segpack, int* __restrict__ hist) {
    __shared__ float t1[NCONST], t2[NCONST];
    __shared__ int lh[64];
    int tid = threadIdx.x;
    if (tid < NCONST) {
        float w = w1a[tid]; t1[tid] = (w != 0.f) ? (-b1a[tid] / w) : INFINITY;
        float v = w2a[tid]; t2[tid] = (v != 0.f) ? (-b2a[tid] / v) : INFINITY;
    }
    if (tid < 64) lh[tid] = 0;
    __syncthreads();
    int e = blockIdx.x * blockDim.x + tid;
    bool valid = e < E;
    if (valid) {
        float a = ea[e];
        int j1 = 0, j2 = 0;
        for (int k = 0; k < NCONST; ++k) { j1 += (t1[k] < a); j2 += (t2[k] < a); }
        segpack[e] = j1 | (j2 << 8);
        atomicAdd(&lh[j1], 1); atomicAdd(&lh[32 + j2], 1);
    }
    __syncthreads();
    if (tid < 64 && lh[tid]) atomicAdd(&hist[tid], lh[tid]);
}

// Parallel hist load through LDS, then two lanes do the 26-step chunk-aligned
// exclusive scan LDS-resident.
__global__ void scanpad_kernel(const int* __restrict__ hist, int* __restrict__ cur) {
    __shared__ int h[64];
    int tid = threadIdx.x;
    h[tid] = hist[tid];
    __syncthreads();
    if (tid == 0) {
        int off = 0;
        for (int j = 0; j < 26; ++j) { cur[j] = off; off += ((h[j] + CH1 - 1) / CH1) * CH1; }
    } else if (tid == 1) {
        int off = 0;
        for (int j = 0; j < 26; ++j) { cur[32 + j] = off; off += ((h[32 + j] + CH2 - 1) / CH2) * CH2; }
    }
}

// Block-aggregated scatter: LDS rank + one global atomicAdd per (block,bin).
__global__ void scatter_kernel(const int* __restrict__ segpack, int E, int* __restrict__ cur,
                               int* __restrict__ order1, int* __restrict__ order2) {
    __shared__ int lh[64], lb[64];
    int tid = threadIdx.x;
    if (tid < 64) lh[tid] = 0;
    __syncthreads();
    int e = blockIdx.x * blockDim.x + tid;
    bool valid = e < E;
    int j1 = 0, j2 = 0, r1 = 0, r2 = 0;
    if (valid) {
        int p = segpack[e]; j1 = p & 0xFF; j2 = p >> 8;
        r1 = atomicAdd(&lh[j1], 1); r2 = atomicAdd(&lh[32 + j2], 1);
    }
    __syncthreads();
    if (tid < 64 && lh[tid]) lb[tid] = atomicAdd(&cur[tid], lh[tid]);
    __syncthreads();
    if (valid) {
        order1[lb[j1] + r1] = (j1 << 17) | e;
        order2[lb[32 + j2] + r2] = (j2 << 17) | e;
    }
}

// U_s = sum_{k active} wa_k*wb_k ; V_s = sum_{k active} ba_k*wb_k + bb.
__global__ void build_uv_fused(const float* w1a, const float* b1a, const float* w1b, const float* b1b,
                               const float* w2a, const float* b2a, const float* w2b, const float* b2b,
                               float* U1, float* V1, float* U2, float* V2) {
    __shared__ float swa[NCONST], sba[NCONST], st[NCONST];
    __shared__ int sr[NCONST];
    __shared__ unsigned msk_sh;
    int seg = blockIdx.y;
    int bx = blockIdx.x;
    int conv = (bx < 2) ? 0 : 1;
    const float* wa = conv ? w2a : w1a;
    const float* ba = conv ? b2a : b1a;
    int tid = threadIdx.x;
    if (tid < NCONST) {
        float w = wa[tid], b = ba[tid];
        swa[tid] = w; sba[tid] = b;
        st[tid] = (w != 0.f) ? (-b / w) : INFINITY;
    }
    __syncthreads();
    if (tid < NCONST) {
        int rk = 0;
        for (int l = 0; l < NCONST; ++l) rk += (st[l] < st[tid]) ? 1 : 0;
        sr[tid] = rk;
    }
    __syncthreads();
    if (tid == 0) {
        unsigned m = 0;
        for (int k = 0; k < NCONST; ++k) {
            float w = swa[k];
            bool act = (w > 0.f) ? (seg > sr[k])
                     : (w < 0.f) ? (seg <= sr[k])
                                 : (sba[k] > 0.f);
            if (act) m |= (1u << k);
        }
        msk_sh = m;
    }
    __syncthreads();
    unsigned msk = msk_sh;
    if (conv == 0) {
        int idx = bx * 256 + tid;           // < 512
        float u = 0.f, v = 0.f;
        for (int k = 0; k < NCONST; ++k)
            if (msk & (1u << k)) { float w = w1b[k * 512 + idx]; u = fmaf(swa[k], w, u); v = fmaf(sba[k], w, v); }
        v += b1b[idx];
        U1[seg * 512 + idx] = u; V1[seg * 512 + idx] = v;
    } else {
        int idx = (bx - 2) * 256 + tid;     // < 2048
        float u = 0.f, v = 0.f;
        for (int k = 0; k < NCONST; ++k)
            if (msk & (1u << k)) { float w = w2b[k * 2048 + idx]; u = fmaf(swa[k], w, u); v = fmaf(sba[k], w, v); }
        v += b2b[idx];
        U2[seg * 2048 + idx] = u; V2[seg * 2048 + idx] = v;
    }
}

// conv1 edges: IC=16, OC=32, half-wave per edge (2 edges/iter).
__global__ void edge1_kernel(const float* __restrict__ xin, const int* __restrict__ src,
                             const int* __restrict__ tgt, const float* __restrict__ ea,
                             const int* __restrict__ order, int cap,
                             const float* __restrict__ U, const float* __restrict__ V,
                             float* __restrict__ agg) {
    int wid = (blockIdx.x * blockDim.x + threadIdx.x) >> 6;
    int lane = threadIdx.x & 63;
    int base = wid * CH1;
    if (base >= cap) return;
    int pk = order[base + (lane & (CH1 - 1))];
    int p0 = __builtin_amdgcn_readfirstlane(pk);
    if (p0 < 0) return;                        // whole-pad chunk past used region
    int seg = p0 >> 17;
    int ev = (pk < 0) ? 0 : (pk & PACK_MASK);
    int sv = src[ev], tv = tgt[ev];
    float av = ea[ev];
    int half = lane >> 5, c = lane & 31;
    float Ur[16], Vr[16];
    {
        const float* Us = U + seg * 512 + c;
        const float* Vs = V + seg * 512 + c;
#pragma unroll
        for (int i = 0; i < 16; ++i) { Ur[i] = Us[i * 32]; Vr[i] = Vs[i * 32]; }
    }
#pragma unroll
    for (int t = 0; t < CH1; t += 2) {
        int pA = __builtin_amdgcn_readlane(pk, t);
        int pB = __builtin_amdgcn_readlane(pk, t + 1);
        int sA = __builtin_amdgcn_readlane(sv, t);
        int sB = __builtin_amdgcn_readlane(sv, t + 1);
        int tA = __builtin_amdgcn_readlane(tv, t);
        int tB = __builtin_amdgcn_readlane(tv, t + 1);
        float aA = readlane_f(av, t);
        float aB = readlane_f(av, t + 1);
        const float* xA = xin + sA * 16;
        const float* xB = xin + sB * 16;
        float ah = half ? aB : aA;
        int   th = half ? tB : tA;
        int   ph = half ? pB : pA;
        float acc = 0.f;
#pragma unroll
        for (int i = 0; i < 16; ++i) {
            float xi = half ? xB[i] : xA[i];
            acc = fmaf(xi, fmaf(ah, Ur[i], Vr[i]), acc);
        }
        if (ph >= 0) atomicMaxFloat(&agg[th * 32 + c], acc);
    }
}

// conv2 edges: IC=32, OC=64, lane = out channel, A/B edge pair per iteration.
__global__ void edge2_kernel(const float* __restrict__ xin, const int* __restrict__ src,
                             const int* __restrict__ tgt, const float* __restrict__ ea,
                             const int* __restrict__ order, int cap,
                             const float* __restrict__ U, const float* __restrict__ V,
                             float* __restrict__ agg) {
    int wid = (blockIdx.x * blockDim.x + threadIdx.x) >> 6;
    int lane = threadIdx.x & 63;
    int base = wid * CH2;
    if (base >= cap) return;
    int pk = order[base + (lane & (CH2 - 1))];
    int p0 = __builtin_amdgcn_readfirstlane(pk);
    if (p0 < 0) return;
    int seg = p0 >> 17;
    int ev = (pk < 0) ? 0 : (pk & PACK_MASK);
    int sv = src[ev], tv = tgt[ev];
    float av = ea[ev];
    float Ur[32], Vr[32];
    {
        const float* Us = U + seg * 2048 + lane;
        const float* Vs = V + seg * 2048 + lane;
#pragma unroll
        for (int i = 0; i < 32; ++i) { Ur[i] = Us[i * 64]; Vr[i] = Vs[i * 64]; }
    }
#pragma unroll
    for (int t = 0; t < CH2; t += 2) {
        int pA = __builtin_amdgcn_readlane(pk, t);
        int pB = __builtin_amdgcn_readlane(pk, t + 1);
        int sA = __builtin_amdgcn_readlane(sv, t);
        int sB = __builtin_amdgcn_readlane(sv, t + 1);
        int tA = __builtin_amdgcn_readlane(tv, t);
        int tB = __builtin_amdgcn_readlane(tv, t + 1);
        float aA = readlane_f(av, t);
        float aB = readlane_f(av, t + 1);
        const float* xA = xin + sA * 32;
        const float* xB = xin + sB * 32;
        float accA = 0.f, accB = 0.f;
#pragma unroll
        for (int i = 0; i < 32; ++i) {
            accA = fmaf(xA[i], fmaf(aA, Ur[i], Vr[i]), accA);
            accB = fmaf(xB[i], fmaf(aB, Ur[i], Vr[i]), accB);
        }
        if (pA >= 0) atomicMaxFloat(&agg[tA * 64 + lane], accA);
        if (pB >= 0) atomicMaxFloat(&agg[tB * 64 + lane], accB);
    }
}

// conv1 node update: out = elu( fixup(agg) + x @ wr1 + bias1 )
__global__ void node1_kernel(const float* __restrict__ xin, const float* __restrict__ agg,
                             const float* __restrict__ wroot, const float* __restrict__ bias,
                             float* __restrict__ out, int N) {
    int idx = blockIdx.x * blockDim.x + threadIdx.x;
    if (idx >= N * 32) return;
    int n = idx >> 5, c = idx & 31;
    float v = agg[idx];
    if (v == -FLT_MAX) v = 0.f;
    float acc = v + bias[c];
#pragma unroll
    for (int i = 0; i < 16; ++i) acc = fmaf(xin[n * 16 + i], wroot[i * 32 + c], acc);
    out[idx] = acc > 0.f ? acc : expm1f(acc);
}

// Fused tail: node2 (agg fixup + root matmul + elu) -> fc1+elu -> fc2+log_softmax.
// R6/R7: 4 nodes/wave, 16 nodes/block, ZERO local arrays (R4/R5's register-array
// caches were demoted to scratch under the allocator's pinned 64-VGPR budget:
// 677 MB scratch traffic). Weight reuse across the 4 nodes comes from loop
// order: load each weight once per iteration, apply to 4 named accumulators
// with broadcast LDS reads. Peak live set ~50 VGPRs.
__global__ void tail_kernel(const float* __restrict__ h1, const float* __restrict__ agg2,
                            const float* __restrict__ wr2, const float* __restrict__ bias2,
                            const float* __restrict__ fc1w, const float* __restrict__ fc1b,
                            const float* __restrict__ fc2w, const float* __restrict__ fc2b,
                            float* __restrict__ out) {
    __shared__ __align__(16) float h1sh[4][TNB][32];
    __shared__ __align__(16) float h2sh[4][TNB][64];
    __shared__ __align__(16) float h3sh[4][TNB][132];   // +4 pad: n-rows spread banks
    __shared__ __align__(16) float wTsh[10][132];       // fc2w transposed [class][k]
    int tid = threadIdx.x;
    int wv = tid >> 6, lane = tid & 63;

    // one-time staging: wTsh[j][k] = fc2w[k*10+j] (block-cooperative)
    for (int t = tid; t < 1280; t += 256) {
        int k = t / 10, j = t - k * 10;
        wTsh[j][k] = fc2w[t];
    }
    __syncthreads();   // only barrier; everything below is wave-local

    int nb = blockIdx.x * (4 * TNB) + wv * TNB;   // base node of this wave

    // cooperative h1 row stage: TNB*32 = 128 floats = one float2 per lane
    {
        const float2* hp = (const float2*)(h1 + (size_t)nb * 32);
        ((float2*)&h1sh[wv][0][0])[lane] = hp[lane];
    }

    // ---- phase 1: node2. lane = out channel c (0..63), 4 named accs ----
    float b2v = bias2[lane];
    float ac0 = agg2[(size_t)(nb + 0) * 64 + lane];
    float ac1 = agg2[(size_t)(nb + 1) * 64 + lane];
    float ac2 = agg2[(size_t)(nb + 2) * 64 + lane];
    float ac3 = agg2[(size_t)(nb + 3) * 64 + lane];
    ac0 = (ac0 == -FLT_MAX ? 0.f : ac0) + b2v;
    ac1 = (ac1 == -FLT_MAX ? 0.f : ac1) + b2v;
    ac2 = (ac2 == -FLT_MAX ? 0.f : ac2) + b2v;
    ac3 = (ac3 == -FLT_MAX ? 0.f : ac3) + b2v;
#pragma unroll 8
    for (int i = 0; i < 32; ++i) {
        float w = wr2[i * 64 + lane];            // coalesced, L2-hot, 4x reused
        ac0 = fmaf(h1sh[wv][0][i], w, ac0);      // broadcast LDS reads
        ac1 = fmaf(h1sh[wv][1][i], w, ac1);
        ac2 = fmaf(h1sh[wv][2][i], w, ac2);
        ac3 = fmaf(h1sh[wv][3][i], w, ac3);
    }
    h2sh[wv][0][lane] = elu_f(ac0);
    h2sh[wv][1][lane] = elu_f(ac1);
    h2sh[wv][2][lane] = elu_f(ac2);
    h2sh[wv][3][lane] = elu_f(ac3);

    // ---- phase 2: fc1. H2=64 inputs = 16 float4 groups; outputs lane, lane+64 ----
    float fb1 = fc1b[lane], fb2 = fc1b[64 + lane];
    float p0 = fb1, p1 = fb1, p2 = fb1, p3 = fb1;
    float q0 = fb2, q1 = fb2, q2 = fb2, q3 = fb2;
#pragma unroll 2
    for (int k4 = 0; k4 < 16; ++k4) {
        int k = k4 * 4;
        float wA0 = fc1w[(k + 0) * 128 + lane];
        float wB0 = fc1w[(k + 0) * 128 + 64 + lane];
        float wA1 = fc1w[(k + 1) * 128 + lane];
        float wB1 = fc1w[(k + 1) * 128 + 64 + lane];
        float wA2 = fc1w[(k + 2) * 128 + lane];
        float wB2 = fc1w[(k + 2) * 128 + 64 + lane];
        float wA3 = fc1w[(k + 3) * 128 + lane];
        float wB3 = fc1w[(k + 3) * 128 + 64 + lane];
        float4 g0 = ((const float4*)h2sh[wv][0])[k4];   // broadcast LDS b128
        float4 g1 = ((const float4*)h2sh[wv][1])[k4];
        float4 g2 = ((const float4*)h2sh[wv][2])[k4];
        float4 g3 = ((const float4*)h2sh[wv][3])[k4];
        p0 = fmaf(g0.x, wA0, p0); p0 = fmaf(g0.y, wA1, p0);
        p0 = fmaf(g0.z, wA2, p0); p0 = fmaf(g0.w, wA3, p0);
        q0 = fmaf(g0.x, wB0, q0); q0 = fmaf(g0.y, wB1, q0);
        q0 = fmaf(g0.z, wB2, q0); q0 = fmaf(g0.w, wB3, q0);
        p1 = fmaf(g1.x, wA0, p1); p1 = fmaf(g1.y, wA1, p1);
        p1 = fmaf(g1.z, wA2, p1); p1 = fmaf(g1.w, wA3, p1);
        q1 = fmaf(g1.x, wB0, q1); q1 = fmaf(g1.y, wB1, q1);
        q1 = fmaf(g1.z, wB2, q1); q1 = fmaf(g1.w, wB3, q1);
        p2 = fmaf(g2.x, wA0, p2); p2 = fmaf(g2.y, wA1, p2);
        p2 = fmaf(g2.z, wA2, p2); p2 = fmaf(g2.w, wA3, p2);
        q2 = fmaf(g2.x, wB0, q2); q2 = fmaf(g2.y, wB1, q2);
        q2 = fmaf(g2.z, wB2, q2); q2 = fmaf(g2.w, wB3, q2);
        p3 = fmaf(g3.x, wA0, p3); p3 = fmaf(g3.y, wA1, p3);
        p3 = fmaf(g3.z, wA2, p3); p3 = fmaf(g3.w, wA3, p3);
        q3 = fmaf(g3.x, wB0, q3); q3 = fmaf(g3.y, wB1, q3);
        q3 = fmaf(g3.z, wB2, q3); q3 = fmaf(g3.w, wB3, q3);
    }
    h3sh[wv][0][lane] = elu_f(p0); h3sh[wv][0][64 + lane] = elu_f(q0);
    h3sh[wv][1][lane] = elu_f(p1); h3sh[wv][1][64 + lane] = elu_f(q1);
    h3sh[wv][2][lane] = elu_f(p2); h3sh[wv][2][64 + lane] = elu_f(q2);
    h3sh[wv][3][lane] = elu_f(p3); h3sh[wv][3][64 + lane] = elu_f(q3);

    // ---- phase 3: fc2 + log_softmax. lane -> (n = lane>>4, j = lane&15) ----
    {
        int n = lane >> 4, j = lane & 15;
        bool act = j < 10;
        int jc = act ? j : 0;
        float a = fc2b[jc];
        const float4* h3v = (const float4*)h3sh[wv][n];
        const float4* wv4 = (const float4*)wTsh[jc];
#pragma unroll
        for (int q = 0; q < 32; ++q) {
            float4 h = h3v[q];
            float4 w = wv4[q];
            a = fmaf(h.x, w.x, a);
            a = fmaf(h.y, w.y, a);
            a = fmaf(h.z, w.z, a);
            a = fmaf(h.w, w.w, a);
        }
        float lm = act ? a : -FLT_MAX;
        lm = fmaxf(lm, __shfl_xor(lm, 1, 16));
        lm = fmaxf(lm, __shfl_xor(lm, 2, 16));
        lm = fmaxf(lm, __shfl_xor(lm, 4, 16));
        lm = fmaxf(lm, __shfl_xor(lm, 8, 16));
        float ls = act ? expf(a - lm) : 0.f;
        ls += __shfl_xor(ls, 1, 16);
        ls += __shfl_xor(ls, 2, 16);
        ls += __shfl_xor(ls, 4, 16);
        ls += __shfl_xor(ls, 8, 16);
        if (act) out[(size_t)(nb + n) * 10 + j] = a - lm - logf(ls);
    }
}

extern "C" void kernel_launch(void* const* d_in, const int* in_sizes, int n_in,
                              void* d_out, int out_size, void* d_ws, size_t ws_size,
                              hipStream_t stream) {
    const float* x     = (const float*)d_in[0];
    const int*   eidx  = (const int*)d_in[1];
    const float* ea    = (const float*)d_in[2];
    const float* w1a   = (const float*)d_in[3];
    const float* b1a   = (const float*)d_in[4];
    const float* w1b   = (const float*)d_in[5];
    const float* b1b   = (const float*)d_in[6];
    const float* wr1   = (const float*)d_in[7];
    const float* bias1 = (const float*)d_in[8];
    const float* w2a   = (const float*)d_in[9];
    const float* b2a   = (const float*)d_in[10];
    const float* w2b   = (const float*)d_in[11];
    const float* b2b   = (const float*)d_in[12];
    const float* wr2   = (const float*)d_in[13];
    const float* bias2 = (const float*)d_in[14];
    const float* fc1w  = (const float*)d_in[15];
    const float* fc1b  = (const float*)d_in[16];
    const float* fc2w  = (const float*)d_in[17];
    const float* fc2b  = (const float*)d_in[18];

    const int N = in_sizes[0] / 16;   // 20000
    const int E = in_sizes[2];        // 100000
    const int* src = eidx;
    const int* tgt = eidx + E;

    const int cap1 = ((E + 26 * (CH1 - 1)) + CH1 - 1) / CH1 * CH1;
    const int cap2 = ((E + 26 * (CH2 - 1)) + CH2 - 1) / CH2 * CH2;

    float* ws = (float*)d_ws;
    size_t off = 0;
    int*      hist = (int*)(ws + off);      off += 64;
    int*      cur  = (int*)(ws + off);      off += 64;
    int*      segp = (int*)(ws + off);      off += E;
    int*      ord1 = (int*)(ws + off);      off += cap1;   // ord1/ord2 contiguous
    int*      ord2 = (int*)(ws + off);      off += cap2;
    float*    U1   = ws + off;              off += 26 * 512;
    float*    V1   = ws + off;              off += 26 * 512;
    float*    U2   = ws + off;              off += 26 * 2048;
    float*    V2   = ws + off;              off += 26 * 2048;
    float*    AGG1 = ws + off;              off += (size_t)N * 32;   // AGG1/AGG2 contiguous
    float*    AGG2 = ws + off;              off += (size_t)N * 64;
    float*    H1b  = ws + off;              off += (size_t)N * 32;

    // 1. init: agg=-FLT_MAX, order arrays=-1, hist=0
    fill_kernel<<<512, 256, 0, stream>>>(AGG1, N * 96, ord1, cap1 + cap2, hist, 64);
    // 2. per-edge segment ranks + histograms
    assign_hist_kernel<<<(E + 255) / 256, 256, 0, stream>>>(ea, w1a, b1a, w2a, b2a, E, segp, hist);
    // 3. chunk-aligned bucket offsets
    scanpad_kernel<<<1, 64, 0, stream>>>(hist, cur);
    // 4. scatter edges into segment-sorted order arrays
    scatter_kernel<<<(E + 255) / 256, 256, 0, stream>>>(segp, E, cur, ord1, ord2);
    // 5. per-segment U/V tables, both convs
    build_uv_fused<<<dim3(10, 26), 256, 0, stream>>>(w1a, b1a, w1b, b1b, w2a, b2a, w2b, b2b,
                                                     U1, V1, U2, V2);
    // 6. conv1
    {
        int waves = cap1 / CH1;
        edge1_kernel<<<(waves + 3) / 4, 256, 0, stream>>>(x, src, tgt, ea, ord1, cap1, U1, V1, AGG1);
    }
    node1_kernel<<<(N * 32 + 255) / 256, 256, 0, stream>>>(x, AGG1, wr1, bias1, H1b, N);
    // 7. conv2
    {
        int waves = cap2 / CH2;
        edge2_kernel<<<(waves + 3) / 4, 256, 0, stream>>>(H1b, src, tgt, ea, ord2, cap2, U2, V2, AGG2);
    }
    // 8. fused node2 + fc1 + fc2 + log_softmax (N % 16 == 0 -> 16 nodes/block)
    tail_kernel<<<N / 16, 256, 0, stream>>>(H1b, AGG2, wr2, bias2, fc1w, fc1b, fc2w, fc2b, (float*)d_out);
}